// Round 6
// baseline (1446.362 us; speedup 1.0000x reference)
//
#include <hip/hip_runtime.h>

#define N_NODE 50000
#define N_EDGE 400000
#define INF    128

// segment tiling (32 rows/tile), boundaries are compile-time: 10000 / 20000 / 50000
#define TILES0 313
#define TILES1 313
#define TILES2 938
#define NTILES 1564

#define FUSED_BLOCKS 1536   // 6 blocks/CU at <=85 VGPR (launch_bounds 256,6)
#define QA_BLOCKS    1024

__device__ __forceinline__ void seg_decode(int b, int& ty, int& base, int& nrows) {
  if (b < TILES0)            { ty = 0; base = b * 32;                      nrows = 10000 - base; }
  else if (b < TILES0+TILES1){ ty = 1; base = 10000 + (b - TILES0) * 32;   nrows = 20000 - base; }
  else                       { ty = 2; base = 20000 + (b - TILES0-TILES1)*32; nrows = 50000 - base; }
  if (nrows > 32) nrows = 32;
}

__device__ __forceinline__ float blo(unsigned u) { return __uint_as_float(u << 16); }
__device__ __forceinline__ float bhi(unsigned u) { return __uint_as_float(u & 0xffff0000u); }
// pack two f32 -> bf16x2 (RNE), lo = even dim, hi = odd dim
__device__ __forceinline__ unsigned bpack(float lo, float hi) {
  unsigned a = __float_as_uint(lo), b = __float_as_uint(hi);
  a = (a + 0x7fffu + ((a >> 16) & 1u)) >> 16;
  b = (b + 0x7fffu + ((b >> 16) & 1u)) & 0xffff0000u;
  return a | b;
}

// ---- concat features into x (= d_out), grid-stride -----------------------
__global__ __launch_bounds__(256) void k_concat(const float* __restrict__ dr,
                                                const float* __restrict__ di,
                                                const float* __restrict__ pr,
                                                float* __restrict__ x) {
  for (int i = blockIdx.x * 256 + threadIdx.x; i < N_NODE * 32; i += 2048 * 256) {
    int row = i >> 5;
    float4 val;
    if (row < 10000)      val = ((const float4*)dr)[i];
    else if (row < 20000) val = ((const float4*)di)[i - 10000*32];
    else                  val = ((const float4*)pr)[i - 20000*32];
    ((float4*)x)[i] = val;
  }
}

// ---- CSR build -----------------------------------------------------------
__global__ __launch_bounds__(256) void k_count(const int* __restrict__ dst, int* __restrict__ deg) {
  int e = blockIdx.x * 256 + threadIdx.x;
  if (e < N_EDGE) atomicAdd(&deg[dst[e]], 1);
}

__global__ __launch_bounds__(1024) void k_scan(const int* __restrict__ deg,
                                               int* __restrict__ off, int* __restrict__ cur) {
  __shared__ int part[1024];
  int t = threadIdx.x;
  int c0 = t * 49;
  int c1 = c0 + 49; if (c1 > N_NODE) c1 = N_NODE;
  int s = 0;
  for (int i = c0; i < c1; ++i) s += deg[i];
  part[t] = s;
  __syncthreads();
  for (int ofs = 1; ofs < 1024; ofs <<= 1) {
    int v = (t >= ofs) ? part[t - ofs] : 0;
    __syncthreads();
    part[t] += v;
    __syncthreads();
  }
  int run = (t == 0) ? 0 : part[t - 1];
  for (int i = c0; i < c1; ++i) { off[i] = run; cur[i] = run; run += deg[i]; }
  if (t == 1023) off[N_NODE] = part[1023];
}

// writes combined edge record est[p] = (src<<2) | etype
__global__ __launch_bounds__(256) void k_fill(const int* __restrict__ dst,
                                              const int* __restrict__ src,
                                              const int* __restrict__ etp,
                                              int* __restrict__ cur, int* __restrict__ est) {
  int e = blockIdx.x * 256 + threadIdx.x;
  if (e < N_EDGE) {
    int p = atomicAdd(&cur[dst[e]], 1);
    est[p] = (src[e] << 2) | etp[e];
  }
}

// ---- transpose rel_msg: AmT[h][ty][do][di] = rel_msg[h][ty][di][do] ------
__global__ __launch_bounds__(256) void k_trmsg(const float* __restrict__ rm,
                                               float* __restrict__ AmT) {
  int i = blockIdx.x * 256 + threadIdx.x;   // 8192 total
  int di = i & 15, doo = (i >> 4) & 15, ty = (i >> 8) & 3, hh = i >> 10;
  AmT[i] = rm[((hh * 4 + ty) * 16 + di) * 16 + doo];
}

// ---- typed K/Q/V projection; k,v,q packed bf16 ---------------------------
// kvb[n] = 64 x uint2 : elem l = { bf16x2(k[2l],k[2l+1]), bf16x2(v[2l],v[2l+1]) }
// qbh[n] = 64 x uint  : elem l = bf16x2(q[2l],q[2l+1])
__global__ __launch_bounds__(256) void k_qkv(const float* __restrict__ x,
                                             const float* __restrict__ Wk,
                                             const float* __restrict__ Wq,
                                             const float* __restrict__ Wv,
                                             uint2* __restrict__ kvb,
                                             unsigned* __restrict__ qbh) {
  __shared__ float xs[32][128];
  int ty, base, nrows;
  seg_decode(blockIdx.x, ty, base, nrows);
  int t = threadIdx.x;
#pragma unroll
  for (int it = 0; it < 4; ++it) {
    int idx4 = t + it * 256;
    int row = idx4 >> 5, c4 = idx4 & 31;
    float4 val = make_float4(0.f, 0.f, 0.f, 0.f);
    if (row < nrows) val = ((const float4*)(x + (size_t)(base + row) * INF))[c4];
    ((float4*)&xs[row][0])[c4] = val;
  }
  __syncthreads();
  int o = t & 127, g = t >> 7;
  float ak[16], aq[16], av[16];
#pragma unroll
  for (int j = 0; j < 16; ++j) { ak[j] = 0.f; aq[j] = 0.f; av[j] = 0.f; }
  const float* WK = Wk + ty * 16384;
  const float* WQ = Wq + ty * 16384;
  const float* WV = Wv + ty * 16384;
  for (int i0 = 0; i0 < 32; ++i0) {
    float wk[4], wq[4], wv[4];
#pragma unroll
    for (int di = 0; di < 4; ++di) {
      int i = i0 * 4 + di;
      wk[di] = WK[i * 128 + o];
      wq[di] = WQ[i * 128 + o];
      wv[di] = WV[i * 128 + o];
    }
#pragma unroll
    for (int j = 0; j < 16; ++j) {
      float4 x4 = ((const float4*)&xs[g * 16 + j][0])[i0];
      ak[j] += x4.x * wk[0] + x4.y * wk[1] + x4.z * wk[2] + x4.w * wk[3];
      aq[j] += x4.x * wq[0] + x4.y * wq[1] + x4.z * wq[2] + x4.w * wq[3];
      av[j] += x4.x * wv[0] + x4.y * wv[1] + x4.z * wv[2] + x4.w * wv[3];
    }
  }
#pragma unroll
  for (int j = 0; j < 16; ++j) {
    int row = g * 16 + j;
    float akn = __shfl_xor(ak[j], 1);   // neighbor column value (same row)
    float avn = __shfl_xor(av[j], 1);
    float aqn = __shfl_xor(aq[j], 1);
    if (row < nrows && (o & 1) == 0) {
      size_t p = (size_t)(base + row);
      kvb[p * 64 + (o >> 1)] = make_uint2(bpack(ak[j], akn), bpack(av[j], avn));
      qbh[p * 64 + (o >> 1)] = bpack(aq[j], aqn);
    }
  }
}

// ---- qa precompute: qab[n][l] = bf16x2 of (pri[h,ty]/4)*(A[h,ty].q[n]) ----
// lane l: head h=l>>3, j=l&7 -> dims (2j,2j+1) of head h; 4 ty packed in uint4
__global__ __launch_bounds__(256) void k_qa(const unsigned* __restrict__ qbh,
                                            const float* __restrict__ rel_att,
                                            const float* __restrict__ pri,
                                            uint4* __restrict__ qab) {
  int w = threadIdx.x >> 6, l = threadIdx.x & 63;
  int h = l >> 3, j = l & 7;
  float4 prh = ((const float4*)pri)[h];
  float prs[4] = { prh.x * 0.25f, prh.y * 0.25f, prh.z * 0.25f, prh.w * 0.25f };
  for (int n = blockIdx.x * 4 + w; n < N_NODE; n += QA_BLOCKS * 4) {
    const uint4* qp = (const uint4*)qbh + (size_t)n * 16 + h * 2;
    uint4 u0 = qp[0], u1 = qp[1];
    float qf[16];
    qf[0]=blo(u0.x); qf[1]=bhi(u0.x); qf[2]=blo(u0.y); qf[3]=bhi(u0.y);
    qf[4]=blo(u0.z); qf[5]=bhi(u0.z); qf[6]=blo(u0.w); qf[7]=bhi(u0.w);
    qf[8]=blo(u1.x); qf[9]=bhi(u1.x); qf[10]=blo(u1.y); qf[11]=bhi(u1.y);
    qf[12]=blo(u1.z); qf[13]=bhi(u1.z); qf[14]=blo(u1.w); qf[15]=bhi(u1.w);
    unsigned pk[4];
#pragma unroll
    for (int ty = 0; ty < 4; ++ty) {
      const float* Ar = rel_att + (((h * 4 + ty) * 16) + 2 * j) * 16;
      float ax = 0.f, ay = 0.f;
#pragma unroll
      for (int o = 0; o < 16; ++o) {
        ax += Ar[o] * qf[o];
        ay += Ar[16 + o] * qf[o];
      }
      pk[ty] = bpack(ax * prs[ty], ay * prs[ty]);
    }
    qab[(size_t)n * 64 + l] = make_uint4(pk[0], pk[1], pk[2], pk[3]);
  }
}

// ---- fused attention: logits + edge-softmax + aggregation ---------------
// PERSISTENT: FUSED_BLOCKS x 4 waves, 1 wave per node (grid-stride).
// No max-subtraction (logits are O(1); exp can't overflow) -> short chain.
__global__ __launch_bounds__(256, 6) void k_fused(const uint2* __restrict__ kvb,
                                                  const uint4* __restrict__ qab,
                                                  const int* __restrict__ off,
                                                  const int* __restrict__ est,
                                                  const float* __restrict__ AmT,
                                                  float* __restrict__ hb) {
  __shared__ float accs[4][4][128];
  int w = threadIdx.x >> 6, l = threadIdx.x & 63;
  int h = l >> 3, j = l & 7;

  for (int n = blockIdx.x * 4 + w; n < N_NODE; n += FUSED_BLOCKS * 4) {
    int o0 = off[n], o1 = off[n + 1];

    uint4 qu = qab[(size_t)n * 64 + l];
    float2 qa0 = make_float2(blo(qu.x), bhi(qu.x));
    float2 qa1 = make_float2(blo(qu.y), bhi(qu.y));
    float2 qa2 = make_float2(blo(qu.z), bhi(qu.z));
    float2 qa3 = make_float2(blo(qu.w), bhi(qu.w));

    float ssum = 0.f;
    float2 z = make_float2(0.f, 0.f);
    float2 at0 = z, at1 = z, at2 = z, at3 = z;

#define PROC(KV, TY, VALID) { \
    int ty = (TY) & 3; \
    float kx = blo((KV).x), ky = bhi((KV).x); \
    float2 qat = (ty==0)?qa0:(ty==1)?qa1:(ty==2)?qa2:qa3; \
    float part = kx*qat.x + ky*qat.y; \
    part += __shfl_xor(part, 1); \
    part += __shfl_xor(part, 2); \
    part += __shfl_xor(part, 4); \
    float wgt = (VALID) ? __expf(part) : 0.f; \
    ssum += wgt; \
    float vx = blo((KV).y), vy = bhi((KV).y); \
    float w0=(ty==0)?wgt:0.f, w1=(ty==1)?wgt:0.f, w2=(ty==2)?wgt:0.f, w3=(ty==3)?wgt:0.f; \
    at0.x += w0*vx; at0.y += w0*vy; \
    at1.x += w1*vx; at1.y += w1*vy; \
    at2.x += w2*vx; at2.y += w2*vy; \
    at3.x += w3*vx; at3.y += w3*vy; }

    for (int b0 = o0; b0 < o1; b0 += 64) {
      int cnt = o1 - b0; if (cnt > 64) cnt = 64;
      int stv = est[b0 + l];          // est padded by 64 -> no guard needed
      int t0 = __shfl(stv, 0);
      int t1 = __shfl(stv, 1 < cnt ? 1 : 0);
      uint2 kv0 = kvb[(size_t)(t0 >> 2) * 64 + l];
      uint2 kv1 = kvb[(size_t)(t1 >> 2) * 64 + l];
      for (int i = 0; i < cnt; i += 2) {
        bool more = (i + 2) < cnt;        // wave-uniform
        int n0 = 0, n1 = 0; uint2 kn0, kn1;
        if (more) {
          n0 = __shfl(stv, i + 2);
          n1 = __shfl(stv, (i + 3) < cnt ? (i + 3) : (i + 2));
          kn0 = kvb[(size_t)(n0 >> 2) * 64 + l];
          kn1 = kvb[(size_t)(n1 >> 2) * 64 + l];
        }
        PROC(kv0, t0, true)
        PROC(kv1, t1, (i + 1) < cnt)
        if (more) { t0 = n0; t1 = n1; kv0 = kn0; kv1 = kn1; }
      }
    }
#undef PROC

    float inv = (ssum > 0.f) ? 1.f / ssum : 0.f;
    at0.x *= inv; at0.y *= inv;
    at1.x *= inv; at1.y *= inv;
    at2.x *= inv; at2.y *= inv;
    at3.x *= inv; at3.y *= inv;

    // stage per-ty accumulators (wave-private region; no barrier needed)
    ((float2*)&accs[w][0][0])[l] = at0;
    ((float2*)&accs[w][1][0])[l] = at1;
    ((float2*)&accs[w][2][0])[l] = at2;
    ((float2*)&accs[w][3][0])[l] = at3;

    float ox = 0.f, oy = 0.f;
#pragma unroll
    for (int ty = 0; ty < 4; ++ty) {
      const float4* AmR = (const float4*)(AmT + ((h * 4 + ty) * 16) * 16);
#pragma unroll
      for (int d4 = 0; d4 < 4; ++d4) {
        float4 ac = *((float4*)&accs[w][ty][h * 16 + d4 * 4]);
        float4 m0 = AmR[(2 * j) * 4 + d4];
        float4 m1 = AmR[(2 * j + 1) * 4 + d4];
        ox += m0.x * ac.x + m0.y * ac.y + m0.z * ac.z + m0.w * ac.w;
        oy += m1.x * ac.x + m1.y * ac.y + m1.z * ac.z + m1.w * ac.w;
      }
    }
    ((float2*)hb)[(size_t)n * 64 + l] = make_float2(ox, oy);
  }
}

// ---- typed output projection + sigmoid-skip residual (in-place on x) -----
__global__ __launch_bounds__(256) void k_out(const float* __restrict__ hb,
                                             const float* __restrict__ Wa,
                                             const float* __restrict__ skipv,
                                             float* __restrict__ xio) {
  __shared__ float hs[32][128];
  int ty, base, nrows;
  seg_decode(blockIdx.x, ty, base, nrows);
  int t = threadIdx.x;
#pragma unroll
  for (int it = 0; it < 4; ++it) {
    int idx4 = t + it * 256;
    int row = idx4 >> 5, c4 = idx4 & 31;
    float4 val = make_float4(0.f, 0.f, 0.f, 0.f);
    if (row < nrows) val = ((const float4*)(hb + (size_t)(base + row) * INF))[c4];
    ((float4*)&hs[row][0])[c4] = val;
  }
  __syncthreads();
  int o = t & 127, g = t >> 7;
  float acc[16];
#pragma unroll
  for (int j = 0; j < 16; ++j) acc[j] = 0.f;
  const float* WA = Wa + ty * 16384;
  for (int i0 = 0; i0 < 32; ++i0) {
    float wa[4];
#pragma unroll
    for (int di = 0; di < 4; ++di) wa[di] = WA[(i0 * 4 + di) * 128 + o];
#pragma unroll
    for (int j = 0; j < 16; ++j) {
      float4 h4 = ((const float4*)&hs[g * 16 + j][0])[i0];
      acc[j] += h4.x * wa[0] + h4.y * wa[1] + h4.z * wa[2] + h4.w * wa[3];
    }
  }
  float alpha = 1.f / (1.f + __expf(-skipv[ty]));
  float beta = 1.f - alpha;
#pragma unroll
  for (int j = 0; j < 16; ++j) {
    int row = g * 16 + j;
    if (row < nrows) {
      size_t p = (size_t)(base + row) * INF + o;
      xio[p] = acc[j] * alpha + xio[p] * beta;
    }
  }
}

extern "C" void kernel_launch(void* const* d_in, const int* in_sizes, int n_in,
                              void* d_out, int out_size, void* d_ws, size_t ws_size,
                              hipStream_t stream) {
  const float* drug = (const float*)d_in[0];
  const float* dis  = (const float*)d_in[1];
  const float* prot = (const float*)d_in[2];
  const int* src    = (const int*)d_in[3];
  const int* dst    = (const int*)d_in[4];
  const int* etp    = (const int*)d_in[5];
  const float* Wk   = (const float*)d_in[6];
  const float* Wq   = (const float*)d_in[7];
  const float* Wv   = (const float*)d_in[8];
  const float* Wa   = (const float*)d_in[9];
  const float* rel_att = (const float*)d_in[10];
  const float* rel_msg = (const float*)d_in[11];
  const float* pri  = (const float*)d_in[12];
  const float* skip = (const float*)d_in[13];
  float* x = (float*)d_out;

  char* w = (char*)d_ws;
  uint2*    kvb = (uint2*)(w + 0);             // 25,600,000 B
  unsigned* qbh = (unsigned*)(w + 25600000);   // 12,800,000 B
  float*    hb  = (float*)(w + 38400000);      // 25,600,000 B
  uint4*    qab = (uint4*)(w + 64000000);      // 51,200,000 B
  float*    AmT = (float*)(w + 115200000);     //     32,768 B
  int*      off = (int*)(w + 115232768);       //    200,004 B
  int*      est = (int*)(w + 115432776);       //  1,600,256 B (padded by 64)
  // deg/cur alias hb (dead before any layer's k_fused writes hb)
  int*      deg = (int*)(w + 38400000);        //    200,000 B
  int*      cur = (int*)(w + 38600064);        //    200,000 B

  // x = concat(features)
  k_concat<<<2048, 256, 0, stream>>>(drug, dis, prot, x);

  // CSR by dst (edges constant across layers)
  hipMemsetAsync(deg, 0, N_NODE * sizeof(int), stream);
  hipMemsetAsync(est + N_EDGE, 0, 64 * sizeof(int), stream);
  k_count<<<(N_EDGE + 255) / 256, 256, 0, stream>>>(dst, deg);
  k_scan<<<1, 1024, 0, stream>>>(deg, off, cur);
  k_fill<<<(N_EDGE + 255) / 256, 256, 0, stream>>>(dst, src, etp, cur, est);

  // rel_msg transpose (constant across layers)
  k_trmsg<<<32, 256, 0, stream>>>(rel_msg, AmT);

  for (int layer = 0; layer < 2; ++layer) {
    k_qkv<<<NTILES, 256, 0, stream>>>(x, Wk, Wq, Wv, kvb, qbh);
    k_qa<<<QA_BLOCKS, 256, 0, stream>>>(qbh, rel_att, pri, qab);
    k_fused<<<FUSED_BLOCKS, 256, 0, stream>>>(kvb, qab, off, est, AmT, hb);
    k_out<<<NTILES, 256, 0, stream>>>(hb, Wa, skip, x);
  }
}

// Round 7
// 1049.264 us; speedup vs baseline: 1.3785x; 1.3785x over previous
//
#include <hip/hip_runtime.h>

#define N_NODE 50000
#define N_EDGE 400000
#define INF    128

// segment tiling (32 rows/tile), boundaries are compile-time: 10000 / 20000 / 50000
#define TILES0 313
#define TILES1 313
#define TILES2 938
#define NTILES 1564

#define FUSED_BLOCKS 2048   // 8 blocks/CU at <=64 VGPR; >=4 resident guaranteed
#define QA_BLOCKS    1024

__device__ __forceinline__ void seg_decode(int b, int& ty, int& base, int& nrows) {
  if (b < TILES0)            { ty = 0; base = b * 32;                      nrows = 10000 - base; }
  else if (b < TILES0+TILES1){ ty = 1; base = 10000 + (b - TILES0) * 32;   nrows = 20000 - base; }
  else                       { ty = 2; base = 20000 + (b - TILES0-TILES1)*32; nrows = 50000 - base; }
  if (nrows > 32) nrows = 32;
}

__device__ __forceinline__ float blo(unsigned u) { return __uint_as_float(u << 16); }
__device__ __forceinline__ float bhi(unsigned u) { return __uint_as_float(u & 0xffff0000u); }
// pack two f32 -> bf16x2 (RNE), lo = even dim, hi = odd dim
__device__ __forceinline__ unsigned bpack(float lo, float hi) {
  unsigned a = __float_as_uint(lo), b = __float_as_uint(hi);
  a = (a + 0x7fffu + ((a >> 16) & 1u)) >> 16;
  b = (b + 0x7fffu + ((b >> 16) & 1u)) & 0xffff0000u;
  return a | b;
}

// ---- concat features into x (= d_out), grid-stride -----------------------
__global__ __launch_bounds__(256) void k_concat(const float* __restrict__ dr,
                                                const float* __restrict__ di,
                                                const float* __restrict__ pr,
                                                float* __restrict__ x) {
  for (int i = blockIdx.x * 256 + threadIdx.x; i < N_NODE * 32; i += 2048 * 256) {
    int row = i >> 5;
    float4 val;
    if (row < 10000)      val = ((const float4*)dr)[i];
    else if (row < 20000) val = ((const float4*)di)[i - 10000*32];
    else                  val = ((const float4*)pr)[i - 20000*32];
    ((float4*)x)[i] = val;
  }
}

// ---- CSR build -----------------------------------------------------------
__global__ __launch_bounds__(256) void k_count(const int* __restrict__ dst, int* __restrict__ deg) {
  int e = blockIdx.x * 256 + threadIdx.x;
  if (e < N_EDGE) atomicAdd(&deg[dst[e]], 1);
}

__global__ __launch_bounds__(1024) void k_scan(const int* __restrict__ deg,
                                               int* __restrict__ off, int* __restrict__ cur) {
  __shared__ int part[1024];
  int t = threadIdx.x;
  int c0 = t * 49;
  int c1 = c0 + 49; if (c1 > N_NODE) c1 = N_NODE;
  int s = 0;
  for (int i = c0; i < c1; ++i) s += deg[i];
  part[t] = s;
  __syncthreads();
  for (int ofs = 1; ofs < 1024; ofs <<= 1) {
    int v = (t >= ofs) ? part[t - ofs] : 0;
    __syncthreads();
    part[t] += v;
    __syncthreads();
  }
  int run = (t == 0) ? 0 : part[t - 1];
  for (int i = c0; i < c1; ++i) { off[i] = run; cur[i] = run; run += deg[i]; }
  if (t == 1023) off[N_NODE] = part[1023];
}

// writes combined edge record est[p] = (src<<2) | etype
__global__ __launch_bounds__(256) void k_fill(const int* __restrict__ dst,
                                              const int* __restrict__ src,
                                              const int* __restrict__ etp,
                                              int* __restrict__ cur, int* __restrict__ est) {
  int e = blockIdx.x * 256 + threadIdx.x;
  if (e < N_EDGE) {
    int p = atomicAdd(&cur[dst[e]], 1);
    est[p] = (src[e] << 2) | etp[e];
  }
}

// ---- transpose rel_msg: AmT[h][ty][do][di] = rel_msg[h][ty][di][do] ------
__global__ __launch_bounds__(256) void k_trmsg(const float* __restrict__ rm,
                                               float* __restrict__ AmT) {
  int i = blockIdx.x * 256 + threadIdx.x;   // 8192 total
  int di = i & 15, doo = (i >> 4) & 15, ty = (i >> 8) & 3, hh = i >> 10;
  AmT[i] = rm[((hh * 4 + ty) * 16 + di) * 16 + doo];
}

// ---- typed K/Q/V projection; k,v,q packed bf16 ---------------------------
// kvb[n] = 64 x uint2 : elem l = { bf16x2(k[2l],k[2l+1]), bf16x2(v[2l],v[2l+1]) }
// qbh[n] = 64 x uint  : elem l = bf16x2(q[2l],q[2l+1])
__global__ __launch_bounds__(256) void k_qkv(const float* __restrict__ x,
                                             const float* __restrict__ Wk,
                                             const float* __restrict__ Wq,
                                             const float* __restrict__ Wv,
                                             uint2* __restrict__ kvb,
                                             unsigned* __restrict__ qbh) {
  __shared__ float xs[32][128];
  int ty, base, nrows;
  seg_decode(blockIdx.x, ty, base, nrows);
  int t = threadIdx.x;
#pragma unroll
  for (int it = 0; it < 4; ++it) {
    int idx4 = t + it * 256;
    int row = idx4 >> 5, c4 = idx4 & 31;
    float4 val = make_float4(0.f, 0.f, 0.f, 0.f);
    if (row < nrows) val = ((const float4*)(x + (size_t)(base + row) * INF))[c4];
    ((float4*)&xs[row][0])[c4] = val;
  }
  __syncthreads();
  int o = t & 127, g = t >> 7;
  float ak[16], aq[16], av[16];
#pragma unroll
  for (int j = 0; j < 16; ++j) { ak[j] = 0.f; aq[j] = 0.f; av[j] = 0.f; }
  const float* WK = Wk + ty * 16384;
  const float* WQ = Wq + ty * 16384;
  const float* WV = Wv + ty * 16384;
  for (int i0 = 0; i0 < 32; ++i0) {
    float wk[4], wq[4], wv[4];
#pragma unroll
    for (int di = 0; di < 4; ++di) {
      int i = i0 * 4 + di;
      wk[di] = WK[i * 128 + o];
      wq[di] = WQ[i * 128 + o];
      wv[di] = WV[i * 128 + o];
    }
#pragma unroll
    for (int j = 0; j < 16; ++j) {
      float4 x4 = ((const float4*)&xs[g * 16 + j][0])[i0];
      ak[j] += x4.x * wk[0] + x4.y * wk[1] + x4.z * wk[2] + x4.w * wk[3];
      aq[j] += x4.x * wq[0] + x4.y * wq[1] + x4.z * wq[2] + x4.w * wq[3];
      av[j] += x4.x * wv[0] + x4.y * wv[1] + x4.z * wv[2] + x4.w * wv[3];
    }
  }
#pragma unroll
  for (int j = 0; j < 16; ++j) {
    int row = g * 16 + j;
    float akn = __shfl_xor(ak[j], 1);   // neighbor column value (same row)
    float avn = __shfl_xor(av[j], 1);
    float aqn = __shfl_xor(aq[j], 1);
    if (row < nrows && (o & 1) == 0) {
      size_t p = (size_t)(base + row);
      kvb[p * 64 + (o >> 1)] = make_uint2(bpack(ak[j], akn), bpack(av[j], avn));
      qbh[p * 64 + (o >> 1)] = bpack(aq[j], aqn);
    }
  }
}

// ---- qa precompute: qab[n][l] = bf16x2 of (pri[h,ty]/4)*(A[h,ty].q[n]) ----
// lane l: head h=l>>3, j=l&7 -> dims (2j,2j+1) of head h; 4 ty packed in uint4
__global__ __launch_bounds__(256) void k_qa(const unsigned* __restrict__ qbh,
                                            const float* __restrict__ rel_att,
                                            const float* __restrict__ pri,
                                            uint4* __restrict__ qab) {
  int w = threadIdx.x >> 6, l = threadIdx.x & 63;
  int h = l >> 3, j = l & 7;
  float4 prh = ((const float4*)pri)[h];
  float prs[4] = { prh.x * 0.25f, prh.y * 0.25f, prh.z * 0.25f, prh.w * 0.25f };
  for (int n = blockIdx.x * 4 + w; n < N_NODE; n += QA_BLOCKS * 4) {
    const uint4* qp = (const uint4*)qbh + (size_t)n * 16 + h * 2;
    uint4 u0 = qp[0], u1 = qp[1];
    float qf[16];
    qf[0]=blo(u0.x); qf[1]=bhi(u0.x); qf[2]=blo(u0.y); qf[3]=bhi(u0.y);
    qf[4]=blo(u0.z); qf[5]=bhi(u0.z); qf[6]=blo(u0.w); qf[7]=bhi(u0.w);
    qf[8]=blo(u1.x); qf[9]=bhi(u1.x); qf[10]=blo(u1.y); qf[11]=bhi(u1.y);
    qf[12]=blo(u1.z); qf[13]=bhi(u1.z); qf[14]=blo(u1.w); qf[15]=bhi(u1.w);
    unsigned pk[4];
#pragma unroll
    for (int ty = 0; ty < 4; ++ty) {
      const float* Ar = rel_att + (((h * 4 + ty) * 16) + 2 * j) * 16;
      float ax = 0.f, ay = 0.f;
#pragma unroll
      for (int o = 0; o < 16; ++o) {
        ax += Ar[o] * qf[o];
        ay += Ar[16 + o] * qf[o];
      }
      pk[ty] = bpack(ax * prs[ty], ay * prs[ty]);
    }
    qab[(size_t)n * 64 + l] = make_uint4(pk[0], pk[1], pk[2], pk[3]);
  }
}

// ---- fused attention: logits + edge-softmax + aggregation ---------------
// PERSISTENT: FUSED_BLOCKS x 4 waves, 1 wave per node (grid-stride).
// launch_bounds(256,4): 128-VGPR cap -> no inner-loop spills (R6 lesson),
// no full-AmT hoist (R5 lesson).
__global__ __launch_bounds__(256, 4) void k_fused(const uint2* __restrict__ kvb,
                                                  const uint4* __restrict__ qab,
                                                  const int* __restrict__ off,
                                                  const int* __restrict__ est,
                                                  const float* __restrict__ AmT,
                                                  float* __restrict__ hb) {
  __shared__ float accs[4][4][128];
  int w = threadIdx.x >> 6, l = threadIdx.x & 63;
  int h = l >> 3, j = l & 7;

  for (int n = blockIdx.x * 4 + w; n < N_NODE; n += FUSED_BLOCKS * 4) {
    int o0 = off[n], o1 = off[n + 1];

    uint4 qu = qab[(size_t)n * 64 + l];
    float2 qa0 = make_float2(blo(qu.x), bhi(qu.x));
    float2 qa1 = make_float2(blo(qu.y), bhi(qu.y));
    float2 qa2 = make_float2(blo(qu.z), bhi(qu.z));
    float2 qa3 = make_float2(blo(qu.w), bhi(qu.w));

    float ssum = 0.f;
    float2 z = make_float2(0.f, 0.f);
    float2 at0 = z, at1 = z, at2 = z, at3 = z;

#define PROC(KV, TY, VALID) { \
    int ty = (TY) & 3; \
    float kx = blo((KV).x), ky = bhi((KV).x); \
    float2 qat = (ty==0)?qa0:(ty==1)?qa1:(ty==2)?qa2:qa3; \
    float part = kx*qat.x + ky*qat.y; \
    part += __shfl_xor(part, 1); \
    part += __shfl_xor(part, 2); \
    part += __shfl_xor(part, 4); \
    float wgt = (VALID) ? __expf(part) : 0.f; \
    ssum += wgt; \
    float vx = blo((KV).y), vy = bhi((KV).y); \
    float w0=(ty==0)?wgt:0.f, w1=(ty==1)?wgt:0.f, w2=(ty==2)?wgt:0.f, w3=(ty==3)?wgt:0.f; \
    at0.x += w0*vx; at0.y += w0*vy; \
    at1.x += w1*vx; at1.y += w1*vy; \
    at2.x += w2*vx; at2.y += w2*vy; \
    at3.x += w3*vx; at3.y += w3*vy; }

    for (int b0 = o0; b0 < o1; b0 += 64) {
      int cnt = o1 - b0; if (cnt > 64) cnt = 64;
      int stv = est[b0 + l];          // est padded by 64 -> no guard needed
      int t0 = __shfl(stv, 0);
      int t1 = __shfl(stv, 1 < cnt ? 1 : 0);
      uint2 kv0 = kvb[(size_t)(t0 >> 2) * 64 + l];
      uint2 kv1 = kvb[(size_t)(t1 >> 2) * 64 + l];
      for (int i = 0; i < cnt; i += 2) {
        bool more = (i + 2) < cnt;        // wave-uniform
        int n0 = 0, n1 = 0; uint2 kn0, kn1;
        if (more) {
          n0 = __shfl(stv, i + 2);
          n1 = __shfl(stv, (i + 3) < cnt ? (i + 3) : (i + 2));
          kn0 = kvb[(size_t)(n0 >> 2) * 64 + l];
          kn1 = kvb[(size_t)(n1 >> 2) * 64 + l];
        }
        PROC(kv0, t0, true)
        PROC(kv1, t1, (i + 1) < cnt)
        if (more) { t0 = n0; t1 = n1; kv0 = kn0; kv1 = kn1; }
      }
    }
#undef PROC

    float inv = (ssum > 0.f) ? 1.f / ssum : 0.f;
    at0.x *= inv; at0.y *= inv;
    at1.x *= inv; at1.y *= inv;
    at2.x *= inv; at2.y *= inv;
    at3.x *= inv; at3.y *= inv;

    // stage per-ty accumulators (wave-private region; no barrier needed)
    ((float2*)&accs[w][0][0])[l] = at0;
    ((float2*)&accs[w][1][0])[l] = at1;
    ((float2*)&accs[w][2][0])[l] = at2;
    ((float2*)&accs[w][3][0])[l] = at3;

    float ox = 0.f, oy = 0.f;
#pragma unroll
    for (int ty = 0; ty < 4; ++ty) {
      const float4* AmR = (const float4*)(AmT + ((h * 4 + ty) * 16) * 16);
#pragma unroll
      for (int d4 = 0; d4 < 4; ++d4) {
        float4 ac = *((float4*)&accs[w][ty][h * 16 + d4 * 4]);
        float4 m0 = AmR[(2 * j) * 4 + d4];
        float4 m1 = AmR[(2 * j + 1) * 4 + d4];
        ox += m0.x * ac.x + m0.y * ac.y + m0.z * ac.z + m0.w * ac.w;
        oy += m1.x * ac.x + m1.y * ac.y + m1.z * ac.z + m1.w * ac.w;
      }
    }
    ((float2*)hb)[(size_t)n * 64 + l] = make_float2(ox, oy);
  }
}

// ---- typed output projection + sigmoid-skip residual (in-place on x) -----
__global__ __launch_bounds__(256) void k_out(const float* __restrict__ hb,
                                             const float* __restrict__ Wa,
                                             const float* __restrict__ skipv,
                                             float* __restrict__ xio) {
  __shared__ float hs[32][128];
  int ty, base, nrows;
  seg_decode(blockIdx.x, ty, base, nrows);
  int t = threadIdx.x;
#pragma unroll
  for (int it = 0; it < 4; ++it) {
    int idx4 = t + it * 256;
    int row = idx4 >> 5, c4 = idx4 & 31;
    float4 val = make_float4(0.f, 0.f, 0.f, 0.f);
    if (row < nrows) val = ((const float4*)(hb + (size_t)(base + row) * INF))[c4];
    ((float4*)&hs[row][0])[c4] = val;
  }
  __syncthreads();
  int o = t & 127, g = t >> 7;
  float acc[16];
#pragma unroll
  for (int j = 0; j < 16; ++j) acc[j] = 0.f;
  const float* WA = Wa + ty * 16384;
  for (int i0 = 0; i0 < 32; ++i0) {
    float wa[4];
#pragma unroll
    for (int di = 0; di < 4; ++di) wa[di] = WA[(i0 * 4 + di) * 128 + o];
#pragma unroll
    for (int j = 0; j < 16; ++j) {
      float4 h4 = ((const float4*)&hs[g * 16 + j][0])[i0];
      acc[j] += h4.x * wa[0] + h4.y * wa[1] + h4.z * wa[2] + h4.w * wa[3];
    }
  }
  float alpha = 1.f / (1.f + __expf(-skipv[ty]));
  float beta = 1.f - alpha;
#pragma unroll
  for (int j = 0; j < 16; ++j) {
    int row = g * 16 + j;
    if (row < nrows) {
      size_t p = (size_t)(base + row) * INF + o;
      xio[p] = acc[j] * alpha + xio[p] * beta;
    }
  }
}

extern "C" void kernel_launch(void* const* d_in, const int* in_sizes, int n_in,
                              void* d_out, int out_size, void* d_ws, size_t ws_size,
                              hipStream_t stream) {
  const float* drug = (const float*)d_in[0];
  const float* dis  = (const float*)d_in[1];
  const float* prot = (const float*)d_in[2];
  const int* src    = (const int*)d_in[3];
  const int* dst    = (const int*)d_in[4];
  const int* etp    = (const int*)d_in[5];
  const float* Wk   = (const float*)d_in[6];
  const float* Wq   = (const float*)d_in[7];
  const float* Wv   = (const float*)d_in[8];
  const float* Wa   = (const float*)d_in[9];
  const float* rel_att = (const float*)d_in[10];
  const float* rel_msg = (const float*)d_in[11];
  const float* pri  = (const float*)d_in[12];
  const float* skip = (const float*)d_in[13];
  float* x = (float*)d_out;

  char* w = (char*)d_ws;
  uint2*    kvb = (uint2*)(w + 0);             // 25,600,000 B
  unsigned* qbh = (unsigned*)(w + 25600000);   // 12,800,000 B
  float*    hb  = (float*)(w + 38400000);      // 25,600,000 B
  uint4*    qab = (uint4*)(w + 64000000);      // 51,200,000 B
  float*    AmT = (float*)(w + 115200000);     //     32,768 B
  int*      off = (int*)(w + 115232768);       //    200,004 B
  int*      est = (int*)(w + 115432776);       //  1,600,256 B (padded by 64)
  // deg/cur alias hb (dead before any layer's k_fused writes hb)
  int*      deg = (int*)(w + 38400000);        //    200,000 B
  int*      cur = (int*)(w + 38600064);        //    200,000 B

  // x = concat(features)
  k_concat<<<2048, 256, 0, stream>>>(drug, dis, prot, x);

  // CSR by dst (edges constant across layers)
  hipMemsetAsync(deg, 0, N_NODE * sizeof(int), stream);
  hipMemsetAsync(est + N_EDGE, 0, 64 * sizeof(int), stream);
  k_count<<<(N_EDGE + 255) / 256, 256, 0, stream>>>(dst, deg);
  k_scan<<<1, 1024, 0, stream>>>(deg, off, cur);
  k_fill<<<(N_EDGE + 255) / 256, 256, 0, stream>>>(dst, src, etp, cur, est);

  // rel_msg transpose (constant across layers)
  k_trmsg<<<32, 256, 0, stream>>>(rel_msg, AmT);

  for (int layer = 0; layer < 2; ++layer) {
    k_qkv<<<NTILES, 256, 0, stream>>>(x, Wk, Wq, Wv, kvb, qbh);
    k_qa<<<QA_BLOCKS, 256, 0, stream>>>(qbh, rel_att, pri, qab);
    k_fused<<<FUSED_BLOCKS, 256, 0, stream>>>(kvb, qab, off, est, AmT, hb);
    k_out<<<NTILES, 256, 0, stream>>>(hb, Wa, skip, x);
  }
}

// Round 9
// 881.870 us; speedup vs baseline: 1.6401x; 1.1898x over previous
//
#include <hip/hip_runtime.h>

#define N_NODE 50000
#define N_EDGE 400000
#define INF    128

#define FUSED_BLOCKS 2048
#define QA_BLOCKS    1024

// 64-row MFMA tiles within type segments (boundaries 10000/20000 are 16-aligned)
#define MT0 157
#define MT1 157
#define MT2 469
#define MTILES 783

typedef __bf16 bf16x8 __attribute__((ext_vector_type(8)));
typedef float  f32x4  __attribute__((ext_vector_type(4)));

__device__ __forceinline__ void seg_decode64(int b, int& ty, int& base, int& nrows) {
  if (b < MT0)          { ty = 0; base = b * 64;                nrows = 10000 - base; }
  else if (b < MT0+MT1) { ty = 1; base = 10000 + (b - MT0)*64;  nrows = 20000 - base; }
  else                  { ty = 2; base = 20000 + (b-MT0-MT1)*64; nrows = 50000 - base; }
  if (nrows > 64) nrows = 64;
}

__device__ __forceinline__ float blo(unsigned u) { return __uint_as_float(u << 16); }
__device__ __forceinline__ float bhi(unsigned u) { return __uint_as_float(u & 0xffff0000u); }
// pack two f32 -> bf16x2 (RNE), lo = even dim, hi = odd dim
__device__ __forceinline__ unsigned bpack(float lo, float hi) {
  unsigned a = __float_as_uint(lo), b = __float_as_uint(hi);
  a = (a + 0x7fffu + ((a >> 16) & 1u)) >> 16;
  b = (b + 0x7fffu + ((b >> 16) & 1u)) & 0xffff0000u;
  return a | b;
}
__device__ __forceinline__ unsigned short b16(float v) {
  unsigned u = __float_as_uint(v);
  return (unsigned short)((u + 0x7fffu + ((u >> 16) & 1u)) >> 16);
}
__device__ __forceinline__ bf16x8 ld_frag(const unsigned short* p) {
  uint4 u = *reinterpret_cast<const uint4*>(p);
  return __builtin_bit_cast(bf16x8, u);
}

// ---- concat features into x (= d_out) + bf16 copy xh, grid-stride --------
__global__ __launch_bounds__(256) void k_concat(const float* __restrict__ dr,
                                                const float* __restrict__ di,
                                                const float* __restrict__ pr,
                                                float* __restrict__ x,
                                                unsigned short* __restrict__ xh) {
  for (int i = blockIdx.x * 256 + threadIdx.x; i < N_NODE * 32; i += 2048 * 256) {
    int row = i >> 5;
    float4 val;
    if (row < 10000)      val = ((const float4*)dr)[i];
    else if (row < 20000) val = ((const float4*)di)[i - 10000*32];
    else                  val = ((const float4*)pr)[i - 20000*32];
    ((float4*)x)[i] = val;
    ((uint2*)xh)[i] = make_uint2(bpack(val.x, val.y), bpack(val.z, val.w));
  }
}

// ---- CSR build -----------------------------------------------------------
__global__ __launch_bounds__(256) void k_count(const int* __restrict__ dst, int* __restrict__ deg) {
  int e = blockIdx.x * 256 + threadIdx.x;
  if (e < N_EDGE) atomicAdd(&deg[dst[e]], 1);
}

__global__ __launch_bounds__(1024) void k_scan(const int* __restrict__ deg,
                                               int* __restrict__ off, int* __restrict__ cur) {
  __shared__ int part[1024];
  int t = threadIdx.x;
  int c0 = t * 49;
  int c1 = c0 + 49; if (c1 > N_NODE) c1 = N_NODE;
  int s = 0;
  for (int i = c0; i < c1; ++i) s += deg[i];
  part[t] = s;
  __syncthreads();
  for (int ofs = 1; ofs < 1024; ofs <<= 1) {
    int v = (t >= ofs) ? part[t - ofs] : 0;
    __syncthreads();
    part[t] += v;
    __syncthreads();
  }
  int run = (t == 0) ? 0 : part[t - 1];
  for (int i = c0; i < c1; ++i) { off[i] = run; cur[i] = run; run += deg[i]; }
  if (t == 1023) off[N_NODE] = part[1023];
}

// writes combined edge record est[p] = (src<<2) | etype
__global__ __launch_bounds__(256) void k_fill(const int* __restrict__ dst,
                                              const int* __restrict__ src,
                                              const int* __restrict__ etp,
                                              int* __restrict__ cur, int* __restrict__ est) {
  int e = blockIdx.x * 256 + threadIdx.x;
  if (e < N_EDGE) {
    int p = atomicAdd(&cur[dst[e]], 1);
    est[p] = (src[e] << 2) | etp[e];
  }
}

// ---- transpose rel_msg: AmT[h][ty][do][di] = rel_msg[h][ty][di][do] ------
__global__ __launch_bounds__(256) void k_trmsg(const float* __restrict__ rm,
                                               float* __restrict__ AmT) {
  int i = blockIdx.x * 256 + threadIdx.x;   // 8192 total
  int di = i & 15, doo = (i >> 4) & 15, ty = (i >> 8) & 3, hh = i >> 10;
  AmT[i] = rm[((hh * 4 + ty) * 16 + di) * 16 + doo];
}

// ---- weight transpose to bf16: WT[(mat*3+ty)*16384 + o*128 + i] ----------
// mats: 0=Wk 1=Wq 2=Wv 3=Wa  (4*3*16384 = 196608 elems)
__global__ __launch_bounds__(256) void k_twt(const float* __restrict__ Wk,
                                             const float* __restrict__ Wq,
                                             const float* __restrict__ Wv,
                                             const float* __restrict__ Wa,
                                             unsigned short* __restrict__ WT) {
  int idx = blockIdx.x * 256 + threadIdx.x;
  if (idx >= 196608) return;
  int mt = idx >> 14;            // mat*3+ty
  int within = idx & 16383;
  int o = within >> 7, ii = within & 127;
  int mat = mt / 3, ty = mt % 3;
  const float* W = (mat == 0) ? Wk : (mat == 1) ? Wq : (mat == 2) ? Wv : Wa;
  WT[idx] = b16(W[ty * 16384 + ii * 128 + o]);
}

// ---- typed K/Q/V projection via MFMA; k,v packed interleaved bf16 --------
// kvb[n][l] = { bf16x2(k[2l],k[2l+1]), bf16x2(v[2l],v[2l+1]) }, qbh bf16x2
__global__ __launch_bounds__(256) void k_qkv(const unsigned short* __restrict__ xh,
                                             const unsigned short* __restrict__ WT,
                                             uint2* __restrict__ kvb,
                                             unsigned* __restrict__ qbh) {
  int ty, base, nrows;
  seg_decode64(blockIdx.x, ty, base, nrows);
  int w = threadIdx.x >> 6, l = threadIdx.x & 63;
  int r16 = l & 15, ks = l >> 4;
  int row0 = base + w * 16;
  int wrows = nrows - w * 16;        // valid rows in this wave's 16-row tile

  bf16x8 a[4];
  const unsigned short* xrow = xh + (size_t)(row0 + r16) * 128 + ks * 8;
#pragma unroll
  for (int kk = 0; kk < 4; ++kk) a[kk] = ld_frag(xrow + kk * 32);

  const unsigned short* WK = WT + (size_t)(0 * 3 + ty) * 16384;
  const unsigned short* WQ = WT + (size_t)(1 * 3 + ty) * 16384;
  const unsigned short* WV = WT + (size_t)(2 * 3 + ty) * 16384;

#pragma unroll 1
  for (int ct = 0; ct < 8; ++ct) {
    int o = ct * 16 + r16;
    const unsigned short* bk = WK + (size_t)o * 128 + ks * 8;
    const unsigned short* bq = WQ + (size_t)o * 128 + ks * 8;
    const unsigned short* bv = WV + (size_t)o * 128 + ks * 8;
    f32x4 ak = {0.f,0.f,0.f,0.f}, aq = {0.f,0.f,0.f,0.f}, av = {0.f,0.f,0.f,0.f};
#pragma unroll
    for (int kk = 0; kk < 4; ++kk) {
      bf16x8 fbk = ld_frag(bk + kk * 32);
      bf16x8 fbq = ld_frag(bq + kk * 32);
      bf16x8 fbv = ld_frag(bv + kk * 32);
      ak = __builtin_amdgcn_mfma_f32_16x16x32_bf16(a[kk], fbk, ak, 0, 0, 0);
      aq = __builtin_amdgcn_mfma_f32_16x16x32_bf16(a[kk], fbq, aq, 0, 0, 0);
      av = __builtin_amdgcn_mfma_f32_16x16x32_bf16(a[kk], fbv, av, 0, 0, 0);
    }
#pragma unroll
    for (int r = 0; r < 4; ++r) {
      int rrel = ks * 4 + r;
      float kn = __shfl_xor(ak[r], 1);
      float qn = __shfl_xor(aq[r], 1);
      float vn = __shfl_xor(av[r], 1);
      if (rrel < wrows && (l & 1) == 0) {
        size_t p = (size_t)(row0 + rrel);
        kvb[p * 64 + (o >> 1)] = make_uint2(bpack(ak[r], kn), bpack(av[r], vn));
        qbh[p * 64 + (o >> 1)] = bpack(aq[r], qn);
      }
    }
  }
}

// ---- qa precompute: qab[n][l] = bf16x2 of (pri[h,ty]/4)*(A[h,ty].q[n]) ----
__global__ __launch_bounds__(256) void k_qa(const unsigned* __restrict__ qbh,
                                            const float* __restrict__ rel_att,
                                            const float* __restrict__ pri,
                                            uint4* __restrict__ qab) {
  int w = threadIdx.x >> 6, l = threadIdx.x & 63;
  int h = l >> 3, j = l & 7;
  float4 prh = ((const float4*)pri)[h];
  float prs[4] = { prh.x * 0.25f, prh.y * 0.25f, prh.z * 0.25f, prh.w * 0.25f };
  for (int n = blockIdx.x * 4 + w; n < N_NODE; n += QA_BLOCKS * 4) {
    const uint4* qp = (const uint4*)qbh + (size_t)n * 16 + h * 2;
    uint4 u0 = qp[0], u1 = qp[1];
    float qf[16];
    qf[0]=blo(u0.x); qf[1]=bhi(u0.x); qf[2]=blo(u0.y); qf[3]=bhi(u0.y);
    qf[4]=blo(u0.z); qf[5]=bhi(u0.z); qf[6]=blo(u0.w); qf[7]=bhi(u0.w);
    qf[8]=blo(u1.x); qf[9]=bhi(u1.x); qf[10]=blo(u1.y); qf[11]=bhi(u1.y);
    qf[12]=blo(u1.z); qf[13]=bhi(u1.z); qf[14]=blo(u1.w); qf[15]=bhi(u1.w);
    unsigned pk[4];
#pragma unroll
    for (int ty = 0; ty < 4; ++ty) {
      const float* Ar = rel_att + (((h * 4 + ty) * 16) + 2 * j) * 16;
      float ax = 0.f, ay = 0.f;
#pragma unroll
      for (int o = 0; o < 16; ++o) {
        ax += Ar[o] * qf[o];
        ay += Ar[16 + o] * qf[o];
      }
      pk[ty] = bpack(ax * prs[ty], ay * prs[ty]);
    }
    qab[(size_t)n * 64 + l] = make_uint4(pk[0], pk[1], pk[2], pk[3]);
  }
}

// ---- fused attention: logits + edge-softmax + aggregation ---------------
// PERSISTENT: FUSED_BLOCKS x 4 waves, 1 wave per node (grid-stride).
__global__ __launch_bounds__(256, 4) void k_fused(const uint2* __restrict__ kvb,
                                                  const uint4* __restrict__ qab,
                                                  const int* __restrict__ off,
                                                  const int* __restrict__ est,
                                                  const float* __restrict__ AmT,
                                                  unsigned* __restrict__ hbh) {
  __shared__ float accs[4][4][128];
  int w = threadIdx.x >> 6, l = threadIdx.x & 63;
  int h = l >> 3, j = l & 7;

  for (int n = blockIdx.x * 4 + w; n < N_NODE; n += FUSED_BLOCKS * 4) {
    int o0 = off[n], o1 = off[n + 1];

    uint4 qu = qab[(size_t)n * 64 + l];
    float2 qa0 = make_float2(blo(qu.x), bhi(qu.x));
    float2 qa1 = make_float2(blo(qu.y), bhi(qu.y));
    float2 qa2 = make_float2(blo(qu.z), bhi(qu.z));
    float2 qa3 = make_float2(blo(qu.w), bhi(qu.w));

    float ssum = 0.f;
    float2 z = make_float2(0.f, 0.f);
    float2 at0 = z, at1 = z, at2 = z, at3 = z;

#define PROC(KV, TY, VALID) { \
    int ty = (TY) & 3; \
    float kx = blo((KV).x), ky = bhi((KV).x); \
    float2 qat = (ty==0)?qa0:(ty==1)?qa1:(ty==2)?qa2:qa3; \
    float part = kx*qat.x + ky*qat.y; \
    part += __shfl_xor(part, 1); \
    part += __shfl_xor(part, 2); \
    part += __shfl_xor(part, 4); \
    float wgt = (VALID) ? __expf(part) : 0.f; \
    ssum += wgt; \
    float vx = blo((KV).y), vy = bhi((KV).y); \
    float w0=(ty==0)?wgt:0.f, w1=(ty==1)?wgt:0.f, w2=(ty==2)?wgt:0.f, w3=(ty==3)?wgt:0.f; \
    at0.x += w0*vx; at0.y += w0*vy; \
    at1.x += w1*vx; at1.y += w1*vy; \
    at2.x += w2*vx; at2.y += w2*vy; \
    at3.x += w3*vx; at3.y += w3*vy; }

    for (int b0 = o0; b0 < o1; b0 += 64) {
      int cnt = o1 - b0; if (cnt > 64) cnt = 64;
      int stv = est[b0 + l];          // est padded by 64 -> no guard needed
      int t0 = __shfl(stv, 0);
      int t1 = __shfl(stv, 1 < cnt ? 1 : 0);
      uint2 kv0 = kvb[(size_t)(t0 >> 2) * 64 + l];
      uint2 kv1 = kvb[(size_t)(t1 >> 2) * 64 + l];
      for (int i = 0; i < cnt; i += 2) {
        bool more = (i + 2) < cnt;        // wave-uniform
        int n0 = 0, n1 = 0; uint2 kn0, kn1;
        if (more) {
          n0 = __shfl(stv, i + 2);
          n1 = __shfl(stv, (i + 3) < cnt ? (i + 3) : (i + 2));
          kn0 = kvb[(size_t)(n0 >> 2) * 64 + l];
          kn1 = kvb[(size_t)(n1 >> 2) * 64 + l];
        }
        PROC(kv0, t0, true)
        PROC(kv1, t1, (i + 1) < cnt)
        if (more) { t0 = n0; t1 = n1; kv0 = kn0; kv1 = kn1; }
      }
    }
#undef PROC

    float inv = (ssum > 0.f) ? 1.f / ssum : 0.f;
    at0.x *= inv; at0.y *= inv;
    at1.x *= inv; at1.y *= inv;
    at2.x *= inv; at2.y *= inv;
    at3.x *= inv; at3.y *= inv;

    ((float2*)&accs[w][0][0])[l] = at0;
    ((float2*)&accs[w][1][0])[l] = at1;
    ((float2*)&accs[w][2][0])[l] = at2;
    ((float2*)&accs[w][3][0])[l] = at3;

    float ox = 0.f, oy = 0.f;
#pragma unroll
    for (int ty = 0; ty < 4; ++ty) {
      const float4* AmR = (const float4*)(AmT + ((h * 4 + ty) * 16) * 16);
#pragma unroll
      for (int d4 = 0; d4 < 4; ++d4) {
        float4 ac = *((float4*)&accs[w][ty][h * 16 + d4 * 4]);
        float4 m0 = AmR[(2 * j) * 4 + d4];
        float4 m1 = AmR[(2 * j + 1) * 4 + d4];
        ox += m0.x * ac.x + m0.y * ac.y + m0.z * ac.z + m0.w * ac.w;
        oy += m1.x * ac.x + m1.y * ac.y + m1.z * ac.z + m1.w * ac.w;
      }
    }
    hbh[(size_t)n * 64 + l] = bpack(ox, oy);   // dims (2l, 2l+1)
  }
}

// ---- typed output projection via MFMA + sigmoid-skip residual ------------
__global__ __launch_bounds__(256) void k_out(const unsigned short* __restrict__ hbh,
                                             const unsigned short* __restrict__ WT,
                                             const float* __restrict__ skipv,
                                             float* __restrict__ xio,
                                             unsigned short* __restrict__ xh) {
  int ty, base, nrows;
  seg_decode64(blockIdx.x, ty, base, nrows);
  int w = threadIdx.x >> 6, l = threadIdx.x & 63;
  int r16 = l & 15, ks = l >> 4;
  int row0 = base + w * 16;
  int wrows = nrows - w * 16;

  bf16x8 a[4];
  const unsigned short* hrow = hbh + (size_t)(row0 + r16) * 128 + ks * 8;
#pragma unroll
  for (int kk = 0; kk < 4; ++kk) a[kk] = ld_frag(hrow + kk * 32);

  const unsigned short* WA = WT + (size_t)(3 * 3 + ty) * 16384;
  float alpha = 1.f / (1.f + __expf(-skipv[ty]));
  float beta = 1.f - alpha;

#pragma unroll 1
  for (int ct = 0; ct < 8; ++ct) {
    int o = ct * 16 + r16;
    const unsigned short* ba = WA + (size_t)o * 128 + ks * 8;
    f32x4 acc = {0.f,0.f,0.f,0.f};
#pragma unroll
    for (int kk = 0; kk < 4; ++kk)
      acc = __builtin_amdgcn_mfma_f32_16x16x32_bf16(a[kk], ld_frag(ba + kk * 32), acc, 0, 0, 0);
#pragma unroll
    for (int r = 0; r < 4; ++r) {
      int rrel = ks * 4 + r;
      size_t p = (size_t)(row0 + rrel) * 128 + o;
      float nx = 0.f;
      if (rrel < wrows) {
        nx = acc[r] * alpha + xio[p] * beta;
        xio[p] = nx;
      }
      float nxn = __shfl_xor(nx, 1);
      if (rrel < wrows && (l & 1) == 0)
        ((unsigned*)xh)[p >> 1] = bpack(nx, nxn);
    }
  }
}

extern "C" void kernel_launch(void* const* d_in, const int* in_sizes, int n_in,
                              void* d_out, int out_size, void* d_ws, size_t ws_size,
                              hipStream_t stream) {
  const float* drug = (const float*)d_in[0];
  const float* dis  = (const float*)d_in[1];
  const float* prot = (const float*)d_in[2];
  const int* src    = (const int*)d_in[3];
  const int* dst    = (const int*)d_in[4];
  const int* etp    = (const int*)d_in[5];
  const float* Wk   = (const float*)d_in[6];
  const float* Wq   = (const float*)d_in[7];
  const float* Wv   = (const float*)d_in[8];
  const float* Wa   = (const float*)d_in[9];
  const float* rel_att = (const float*)d_in[10];
  const float* rel_msg = (const float*)d_in[11];
  const float* pri  = (const float*)d_in[12];
  const float* skip = (const float*)d_in[13];
  float* x = (float*)d_out;

  char* w = (char*)d_ws;
  uint2*          kvb = (uint2*)(w + 0);              // 25,600,000
  unsigned*       qbh = (unsigned*)(w + 25600000);    // 12,800,000
  unsigned*       hbh = (unsigned*)(w + 38400000);    // 12,800,000
  uint4*          qab = (uint4*)(w + 51200000);       // 51,200,000
  unsigned short* xh  = (unsigned short*)(w + 102400000); // 12,800,000
  unsigned short* WT  = (unsigned short*)(w + 115200000); //    393,216
  float*          AmT = (float*)(w + 115593216);      //     32,768
  int*            off = (int*)(w + 115625984);        //    200,004
  int*            est = (int*)(w + 115826048);        //  1,600,256
  // deg/cur alias hbh region (dead until first k_fused write)
  int*            deg = (int*)(w + 38400000);
  int*            cur = (int*)(w + 38600064);

  // x = concat(features), xh = bf16(x)
  k_concat<<<2048, 256, 0, stream>>>(drug, dis, prot, x, xh);

  // CSR by dst (edges constant across layers)
  (void)hipMemsetAsync(deg, 0, N_NODE * sizeof(int), stream);
  (void)hipMemsetAsync(est + N_EDGE, 0, 64 * sizeof(int), stream);
  k_count<<<(N_EDGE + 255) / 256, 256, 0, stream>>>(dst, deg);
  k_scan<<<1, 1024, 0, stream>>>(deg, off, cur);
  k_fill<<<(N_EDGE + 255) / 256, 256, 0, stream>>>(dst, src, etp, cur, est);

  // constant transforms
  k_trmsg<<<32, 256, 0, stream>>>(rel_msg, AmT);
  k_twt<<<768, 256, 0, stream>>>(Wk, Wq, Wv, Wa, WT);

  for (int layer = 0; layer < 2; ++layer) {
    k_qkv<<<MTILES, 256, 0, stream>>>(xh, WT, kvb, qbh);
    k_qa<<<QA_BLOCKS, 256, 0, stream>>>(qbh, rel_att, pri, qab);
    k_fused<<<FUSED_BLOCKS, 256, 0, stream>>>(kvb, qab, off, est, AmT, hbh);
    k_out<<<MTILES, 256, 0, stream>>>((const unsigned short*)hbh, WT, skip, x, xh);
  }
}